// Round 11
// baseline (362.638 us; speedup 1.0000x reference)
//
#include <hip/hip_runtime.h>
#include <hip/hip_bf16.h>
#include <cstdint>

#define DEVINL __device__ __forceinline__

typedef __attribute__((ext_vector_type(8))) short bf16x8;
typedef __attribute__((ext_vector_type(4))) float f32x4;

DEVINL unsigned short f2bf(float f) {
    union { float f; unsigned u; } v; v.f = f;
    unsigned r = v.u + 0x7fffu + ((v.u >> 16) & 1u);   // RNE
    return (unsigned short)(r >> 16);
}
DEVINL float bf2f(unsigned short h) {
    union { unsigned u; float f; } v; v.u = ((unsigned)h) << 16;
    return v.f;
}

constexpr int BN = 256, BK = 32;
constexpr int NSP  = 256;         // H*W
constexpr int SBUF = 256 * 32;    // one sB buffer (u16)

// ---------------------------------------------------------------------------
// Transpose + bf16 convert: x[b][2048][256] f32 -> xT[b][256][2048] bf16.
__global__ __launch_bounds__(256)
void xpose(const float* __restrict__ x, unsigned short* __restrict__ xT)
{
    __shared__ float sh[64][65];
    const int b   = blockIdx.y;
    const int kt  = blockIdx.x & 31;     // 2048/64
    const int ntb = blockIdx.x >> 5;     // 256/64
    const int k0 = kt * 64, n0 = ntb * 64;

    const int r = threadIdx.x >> 4;          // 0..15
    const int c = (threadIdx.x & 15) * 4;    // 0..60

    const float* xb = x + ((size_t)b * 2048 + k0) * 256 + n0;
#pragma unroll
    for (int i = 0; i < 4; ++i) {
        float4 v = *(const float4*)(xb + (size_t)(r + 16 * i) * 256 + c);
        sh[r + 16 * i][c + 0] = v.x;
        sh[r + 16 * i][c + 1] = v.y;
        sh[r + 16 * i][c + 2] = v.z;
        sh[r + 16 * i][c + 3] = v.w;
    }
    __syncthreads();
#pragma unroll
    for (int i = 0; i < 4; ++i) {
        const int rr = r + 16 * i;           // n within tile
        ushort4 o;
        o.x = f2bf(sh[c + 0][rr]);
        o.y = f2bf(sh[c + 1][rr]);
        o.z = f2bf(sh[c + 2][rr]);
        o.w = f2bf(sh[c + 3][rr]);
        *(ushort4*)(xT + ((size_t)b * NSP + n0 + rr) * 2048 + k0 + c) = o;
    }
}

// ---------------------------------------------------------------------------
// Y^T[b][n][m] = sigmoid( sum_k W[b][m][k]*XT[b][n][k] + bias[b][m] ), bf16 out.
// R10's proven structure, BM templated:
//   4 waves x (BM x 64) wave-tiles over a BM x 256 block; BN=256 => W read once.
//   sA double-buffered linear [2][BM][32] (64B rows, uniform banks, no pad);
//   B via global_load_lds (slot-XOR swizzle via pre-swizzled global source);
//   ONE __syncthreads per K-step; LOADA(t+1)/GLOADB(t+1) at step top, STOREA
//   after MFMA (T14 issue-early/store-late); compiler-inserted waits only.
// BM=64 for L1 (big K); BM=32 for tail layers -> 2x blocks, machine-filling.
template<int BM>
__global__ __launch_bounds__(256, 4)
void fc_gemm(const float* __restrict__ Wt, const float* __restrict__ bias,
             const unsigned short* __restrict__ X, unsigned short* __restrict__ Yt,
             int M, int K)
{
    constexpr int AM    = BM / 16;       // frag rows per wave (4 or 2)
    constexpr int AI    = BM / 32;       // float4 A-loads per thread (2 or 1)
    constexpr int SABUF = BM * 32;       // one sA buffer (u16)
    constexpr int EPP   = BM + 8;        // epilogue LDS pitch (u16)

    const int b  = blockIdx.x;
    const int m0 = blockIdx.y * BM;

    // pool: 2 x sA + 2 x sB. Epilogue reuses as [128][EPP].
    __shared__ __align__(128) unsigned short pool[2 * SABUF + 2 * SBUF];
    unsigned short* sA = pool;
    unsigned short* sB = pool + 2 * SABUF;

    const int tid  = threadIdx.x;
    const int lane = tid & 63;
    const int wid  = tid >> 6;            // 0..3
    const int wn   = wid * 64;            // wave's n-offset
    const int fr   = lane & 15;
    const int fo   = (lane >> 4) * 8;     // k-chunk offset (u16)

    // A staging: BM x 32 f32. AI==2: thread owns row tid>>2, 2 chunks (tid&3)*8.
    //            AI==1: thread owns row tid>>3, 1 chunk (tid&7)*4.
    const int am = (AI == 2) ? (tid >> 2) : (tid >> 3);
    const int ac = (AI == 2) ? (tid & 3) * 8 : (tid & 7) * 4;
    const float* Wb = Wt + (size_t)b * M * K + (size_t)m0 * K + (size_t)am * K + ac;

    // B gload source: per-lane row/chunk with slot-XOR pre-swizzle (proven R7)
    const int grow = wid * 64 + (lane >> 2);                 // + i*16
    const int gchk = ((lane & 3) ^ ((lane >> 3) & 3)) * 8;   // elem offset in row
    const unsigned short* Xb = X + (size_t)b * NSP * K;

    // B frag read slot (involution of the write swizzle)
    const int bslot = ((lane >> 4) ^ ((fr >> 1) & 3)) * 8;

    const int NT = K / BK;   // 64/32/16/8

    float4 aS[AI];           // single A staging set (issue-early / store-late)

#define LOADA(k0) { _Pragma("unroll") for (int i = 0; i < AI; ++i) \
                        aS[i] = *(const float4*)(Wb + (k0) + i * 4); }
#define STOREA(p) { \
    if constexpr (AI == 2) { uint4 w_; \
        w_.x = (unsigned)f2bf(aS[0].x) | ((unsigned)f2bf(aS[0].y) << 16); \
        w_.y = (unsigned)f2bf(aS[0].z) | ((unsigned)f2bf(aS[0].w) << 16); \
        w_.z = (unsigned)f2bf(aS[1].x) | ((unsigned)f2bf(aS[1].y) << 16); \
        w_.w = (unsigned)f2bf(aS[1].z) | ((unsigned)f2bf(aS[1].w) << 16); \
        *(uint4*)&sA[(p) * SABUF + am * 32 + ac] = w_; \
    } else { uint2 w_; \
        w_.x = (unsigned)f2bf(aS[0].x) | ((unsigned)f2bf(aS[0].y) << 16); \
        w_.y = (unsigned)f2bf(aS[0].z) | ((unsigned)f2bf(aS[0].w) << 16); \
        *(uint2*)&sA[(p) * SABUF + am * 32 + ac] = w_; } }
#define GLOADB(k0, p) { \
    _Pragma("unroll") for (int i = 0; i < 4; ++i) { \
        const unsigned short* src_ = Xb + (size_t)(grow + i * 16) * K + (k0) + gchk; \
        const unsigned short* dst_ = sB + (p) * SBUF + (wid * 64 + i * 16) * 32; \
        __builtin_amdgcn_global_load_lds( \
            (const __attribute__((address_space(1))) void*)src_, \
            (__attribute__((address_space(3))) void*)dst_, 16, 0, 0); } }

    f32x4 acc[AM][4] = {};

    // Prologue: B(0) + A(0) -> buffers 0; single drain.
    GLOADB(0, 0)
    LOADA(0)
    STOREA(0)
    __syncthreads();

#pragma unroll 1
    for (int t = 0; t < NT; ++t) {
        const int p = t & 1;
        if (t + 1 < NT) { LOADA((t + 1) * BK) GLOADB((t + 1) * BK, p ^ 1) }

        bf16x8 af[AM], bfv[4];
#pragma unroll
        for (int i = 0; i < AM; ++i)
            af[i] = *(const bf16x8*)&sA[p * SABUF + (i * 16 + fr) * 32 + fo];
#pragma unroll
        for (int i = 0; i < 4; ++i)
            bfv[i] = *(const bf16x8*)&sB[p * SBUF + (wn + i * 16 + fr) * 32 + bslot];

#pragma unroll
        for (int mi = 0; mi < AM; ++mi)
#pragma unroll
            for (int ni = 0; ni < 4; ++ni)
                acc[mi][ni] = __builtin_amdgcn_mfma_f32_16x16x32_bf16(af[mi], bfv[ni], acc[mi][ni], 0, 0, 0);

        if (t + 1 < NT) STOREA(p ^ 1)   // A(t+1) had ~full step of cover

        __syncthreads();                // single per-step barrier
    }
#undef LOADA
#undef STOREA
#undef GLOADB

    // ---- Epilogue: bias+sigmoid+pack -> LDS [128][EPP] -> contiguous rows.
    const int hi4 = (lane >> 4) * 4;
#pragma unroll 1
    for (int ph = 0; ph < 2; ++ph) {
        if ((wn >> 7) == ph) {
#pragma unroll
            for (int mi = 0; mi < AM; ++mi) {
#pragma unroll
                for (int ni = 0; ni < 4; ++ni) {
                    const int r  = (wn & 127) + ni * 16 + fr;   // n within phase
                    const int mb = mi * 16 + hi4;               // m within block
                    f32x4 v = acc[mi][ni];
                    ushort4 o;
#pragma unroll
                    for (int q = 0; q < 4; ++q) {
                        float yv = v[q] + bias[(size_t)b * M + m0 + mb + q];
                        yv = 1.0f / (1.0f + __expf(-yv));
                        ((unsigned short*)&o)[q] = f2bf(yv);
                    }
                    *(ushort4*)&pool[r * EPP + mb] = o;
                }
            }
        }
        __syncthreads();
        constexpr int TPR = BM / 8;           // threads per row (8 or 4)
        constexpr int RPI = 256 / TPR;        // rows per iteration (32 or 64)
        const int r = tid / TPR;
        const int c = (tid % TPR) * 8;
#pragma unroll
        for (int it = 0; it < 128 / RPI; ++it) {
            const int rr = r + it * RPI;
            uint4 v = *(const uint4*)&pool[rr * EPP + c];
            *(uint4*)&Yt[((size_t)b * NSP + ph * 128 + rr) * M + m0 + c] = v;
        }
        __syncthreads();
    }
}

// Layer 5: out[b][n] = sum_k act4T[b][n][k] * w5[b][k] + b5[b]   (no sigmoid)
__global__ void fc_final(const unsigned short* __restrict__ A4,
                         const float* __restrict__ W5,
                         const float* __restrict__ B5,
                         float* __restrict__ out)
{
    const int b = blockIdx.x;
    const int t = threadIdx.x;  // 0..255 spatial
    const unsigned short* row = A4 + ((size_t)b * NSP + t) * 128;
    const float* w = W5 + (size_t)b * 128;
    float acc = B5[b];
#pragma unroll
    for (int k = 0; k < 128; k += 8) {
        uint4 v = *(const uint4*)(row + k);
        acc += bf2f((unsigned short)(v.x & 0xffff)) * w[k+0];
        acc += bf2f((unsigned short)(v.x >> 16))    * w[k+1];
        acc += bf2f((unsigned short)(v.y & 0xffff)) * w[k+2];
        acc += bf2f((unsigned short)(v.y >> 16))    * w[k+3];
        acc += bf2f((unsigned short)(v.z & 0xffff)) * w[k+4];
        acc += bf2f((unsigned short)(v.z >> 16))    * w[k+5];
        acc += bf2f((unsigned short)(v.w & 0xffff)) * w[k+6];
        acc += bf2f((unsigned short)(v.w >> 16))    * w[k+7];
    }
    out[b * NSP + t] = acc;
}

extern "C" void kernel_launch(void* const* d_in, const int* in_sizes, int n_in,
                              void* d_out, int out_size, void* d_ws, size_t ws_size,
                              hipStream_t stream)
{
    const float* x  = (const float*)d_in[0];
    const float* w1 = (const float*)d_in[1];
    const float* b1 = (const float*)d_in[2];
    const float* w2 = (const float*)d_in[3];
    const float* b2 = (const float*)d_in[4];
    const float* w3 = (const float*)d_in[5];
    const float* b3 = (const float*)d_in[6];
    const float* w4 = (const float*)d_in[7];
    const float* b4 = (const float*)d_in[8];
    const float* w5 = (const float*)d_in[9];
    const float* b5 = (const float*)d_in[10];

    unsigned short* ws0 = (unsigned short*)d_ws;

    // u16-element offsets. xT dead after L1 -> act2/3/4 reuse its region.
    const size_t XT = (size_t)64 * 256 * 2048;  // 33.55M u16 (67.1 MB)
    unsigned short* xT   = ws0;
    unsigned short* act1 = ws0 + XT;
    unsigned short* act2 = ws0;
    unsigned short* act3 = ws0 + (size_t)64 * 256 * 512;
    unsigned short* act4 = ws0 + (size_t)64 * 256 * (512 + 256);

    xpose<<<dim3(128, 64), dim3(256), 0, stream>>>(x, xT);
    // L1: BM=64, 1024 blocks (machine-filling). Tail: BM=32 doubles block count.
    fc_gemm<64><<<dim3(64, 16), dim3(256), 0, stream>>>(w1, b1, xT,   act1, 1024, 2048);
    fc_gemm<32><<<dim3(64, 16), dim3(256), 0, stream>>>(w2, b2, act1, act2,  512, 1024);
    fc_gemm<32><<<dim3(64,  8), dim3(256), 0, stream>>>(w3, b3, act2, act3,  256,  512);
    fc_gemm<32><<<dim3(64,  4), dim3(256), 0, stream>>>(w4, b4, act3, act4,  128,  256);
    fc_final<<<dim3(64), dim3(256), 0, stream>>>(act4, w5, b5, (float*)d_out);
}